// Round 10
// baseline (157.757 us; speedup 1.0000x reference)
//
#include <hip/hip_runtime.h>

// HausdorffLoss (average): B=8, N=M=4096, C=128, fp32 in/out.
// R10 = R8 loop body (zero-init acc, post-MFMA fmaf epilogue — loads stay
// out of the MFMA dependency cone; R9's max-form serialized them) +
// per-iter col mins to plain-store LDS buffer (one writer per entry),
// single global flush after the K-loop + fused final reduction
// (done-counter). LDS = 40960 B exactly -> 4 blocks/CU.
#define B_ 8
#define N_ 4096
#define M_ 4096
#define C_ 128
#define BN_ (B_ * N_)
#define BM_ (B_ * M_)

typedef __attribute__((ext_vector_type(8))) short bf16x8;    // MFMA A/B frag
typedef __attribute__((ext_vector_type(4))) float floatx4;   // MFMA C/D frag
typedef __attribute__((ext_vector_type(8))) unsigned short ushort8;

// fp32 -> bf16 round-to-nearest-even
__device__ __forceinline__ unsigned short f2bf(float x) {
    unsigned int u = __float_as_uint(x);
    u += 0x7FFFu + ((u >> 16) & 1u);
    return (unsigned short)(u >> 16);
}

// async global->LDS, 16 B per lane; LDS dest = wave-uniform base + lane*16
__device__ __forceinline__ void gl2lds16(const void* g, void* l) {
    __builtin_amdgcn_global_load_lds(
        (const __attribute__((address_space(1))) void*)g,
        (__attribute__((address_space(3))) void*)l, 16, 0, 0);
}

// ---------------------------------------------------------------------------
// Prep: bf16 convert (swizzled: ws[row][g ^ (row&15)] = src[row][g]),
// norms[row] = ||row||^2 (fp32), minbuf[row] = +inf, out & done zero-init.
// Wave handles 4 rows. Grid = (BN_+BM_)/16 = 4096 blocks x 256 threads.
// ---------------------------------------------------------------------------
__global__ __launch_bounds__(256) void prep_kernel(
    const float* __restrict__ S1, const float* __restrict__ S2,
    unsigned int* __restrict__ minbuf, float* __restrict__ norms,
    unsigned short* __restrict__ bfA, unsigned short* __restrict__ bfB,
    float* __restrict__ out, unsigned int* __restrict__ done) {
    const int lane = threadIdx.x & 63;
    const int w    = threadIdx.x >> 6;
    const int gw   = blockIdx.x * 4 + w;
    const int r4   = lane >> 4;
    const int g4   = lane & 15;
    const int row  = gw * 4 + r4;          // 0 .. BN_+BM_-1

    const float* src = (row < BN_) ? S1 + (size_t)row * C_
                                   : S2 + (size_t)(row - BN_) * C_;
    float4 v0 = ((const float4*)src)[g4 * 2];
    float4 v1 = ((const float4*)src)[g4 * 2 + 1];

    float s = v0.x*v0.x + v0.y*v0.y + v0.z*v0.z + v0.w*v0.w
            + v1.x*v1.x + v1.y*v1.y + v1.z*v1.z + v1.w*v1.w;
    s += __shfl_xor(s, 1, 64);
    s += __shfl_xor(s, 2, 64);
    s += __shfl_xor(s, 4, 64);
    s += __shfl_xor(s, 8, 64);

    ushort8 o;
    o[0] = f2bf(v0.x); o[1] = f2bf(v0.y); o[2] = f2bf(v0.z); o[3] = f2bf(v0.w);
    o[4] = f2bf(v1.x); o[5] = f2bf(v1.y); o[6] = f2bf(v1.z); o[7] = f2bf(v1.w);

    unsigned short* dst = (row < BN_) ? bfA + (size_t)row * C_
                                      : bfB + (size_t)(row - BN_) * C_;
    *(ushort8*)&dst[(g4 ^ (row & 15)) * 8] = o;

    if (g4 == 0) { norms[row] = s; minbuf[row] = 0x7F800000u; }
    if (blockIdx.x == 0 && threadIdx.x < B_) {
        out[threadIdx.x] = 0.f;
        done[threadIdx.x] = 0u;
    }
}

// ---------------------------------------------------------------------------
// Main: grid (N/128, M/1024, B). 4 waves; wave tile = 64 rows x 32 cols.
// LDS: two 16 KB B buffers (pre-loop: A tile halves) + 8 KB colbuf2.
// Last block per batch performs the final mean-of-sqrt reduction.
// ---------------------------------------------------------------------------
__global__ __launch_bounds__(256, 2) void hausdorff_mfma(
    const unsigned short* __restrict__ Abf, const unsigned short* __restrict__ Bbf,
    const float* __restrict__ asq_g, const float* __restrict__ bsq_g,
    unsigned int* __restrict__ rowmin, unsigned int* __restrict__ colmin,
    float* __restrict__ out, unsigned int* __restrict__ done_ctr) {

    __shared__ unsigned short B_lds[2][64 * 128];   // 2 x 16 KB
    __shared__ unsigned int colbuf2[2][16 * 64];    // 8 KB, one writer/entry
    // aliases into colbuf2 (dead after the flush):
    unsigned int* s_last = &colbuf2[1][0];
    float* ws4 = (float*)&colbuf2[0][0];

    const int b     = blockIdx.z;
    const int row0  = blockIdx.x * 128;
    const int panel = blockIdx.y;                   // cols panel*1024 ..
    const int tid   = threadIdx.x;
    const int lane  = tid & 63;
    const int w     = tid >> 6;
    const int lm    = lane & 15;
    const int quad  = lane >> 4;
    const int wrow  = (w >> 1) * 64;                // wave's row half
    const int qc    = (w & 1) * 32;                 // wave's col half (of 64)

    const unsigned short* Aws = Abf + ((size_t)b * N_ + row0) * C_;
    const unsigned short* Bws = Bbf + ((size_t)b * M_ + panel * 1024) * C_;

    // ---- stage A through both buffers: rows 0-63 -> buf0, 64-127 -> buf1
    #pragma unroll
    for (int k = 0; k < 4; ++k) {
        const int off = w * 2048 + k * 512;         // ushorts
        gl2lds16(Aws + off + lane * 8,        &B_lds[0][off]);
        gl2lds16(Aws + 8192 + off + lane * 8, &B_lds[1][off]);
    }

    // row norms for this lane's 16 rows: wrow + 16i + 4*quad + reg
    float sa[16];
    #pragma unroll
    for (int i = 0; i < 4; ++i) {
        float4 t = *(const float4*)&asq_g[(size_t)b * N_ + row0 + wrow + 16 * i + 4 * quad];
        sa[4*i+0] = t.x; sa[4*i+1] = t.y; sa[4*i+2] = t.z; sa[4*i+3] = t.w;
    }

    float rv[16];
    #pragma unroll
    for (int v = 0; v < 16; ++v) rv[v] = 1e30f;

    __syncthreads();   // A staged

    // A fragments once; waves 0,1 from buf0 (rows 0-63), waves 2,3 from buf1
    bf16x8 af[4][4];
    {
        const unsigned short* Abuf = &B_lds[w >> 1][0];
        #pragma unroll
        for (int i = 0; i < 4; ++i)
            #pragma unroll
            for (int c = 0; c < 4; ++c)
                af[i][c] = *(const bf16x8*)
                    &Abuf[(16 * i + lm) * 128 + (((c * 4 + quad) ^ lm) * 8)];
    }

    __syncthreads();   // all af reads done -> buffers reusable

    // stage B tile 0 into buf0
    #pragma unroll
    for (int k = 0; k < 4; ++k) {
        const int off = w * 2048 + k * 512;
        gl2lds16(Bws + off + lane * 8, &B_lds[0][off]);
    }
    __syncthreads();   // B0 staged

    for (int it = 0; it < 16; ++it) {
        const int cur = it & 1;
        if (it < 15) {   // stage next tile into the other buffer
            const unsigned short* Bt = Bws + (size_t)(it + 1) * 64 * C_;
            #pragma unroll
            for (int k = 0; k < 4; ++k) {
                const int off = w * 2048 + k * 512;
                gl2lds16(Bt + off + lane * 8, &B_lds[cur ^ 1][off]);
            }
        }
        const int colbase = panel * 1024 + it * 64;
        const float sb0 = bsq_g[(size_t)b * M_ + colbase + qc + lm];
        const float sb1 = bsq_g[(size_t)b * M_ + colbase + qc + 16 + lm];

        bf16x8 bf[2][4];
        #pragma unroll
        for (int j = 0; j < 2; ++j)
            #pragma unroll
            for (int c = 0; c < 4; ++c)
                bf[j][c] = *(const bf16x8*)
                    &B_lds[cur][(qc + 16 * j + lm) * 128 + (((c * 4 + quad) ^ lm) * 8)];

        floatx4 acc[4][2] = {};
        #pragma unroll
        for (int c = 0; c < 4; ++c)
            #pragma unroll
            for (int i = 0; i < 4; ++i)
                #pragma unroll
                for (int j = 0; j < 2; ++j)
                    acc[i][j] = __builtin_amdgcn_mfma_f32_16x16x32_bf16(
                        af[i][c], bf[j][c], acc[i][j], 0, 0, 0);

        float cv0 = 1e30f, cv1 = 1e30f;
        #pragma unroll
        for (int i = 0; i < 4; ++i)
            #pragma unroll
            for (int reg = 0; reg < 4; ++reg) {
                const int v = 4 * i + reg;
                float d0 = fmaf(-2.0f, acc[i][0][reg], sa[v] + sb0);
                float d1 = fmaf(-2.0f, acc[i][1][reg], sa[v] + sb1);
                rv[v] = fminf(rv[v], fminf(d0, d1));   // -> v_min3
                cv0 = fminf(cv0, d0);
                cv1 = fminf(cv1, d1);
            }
        cv0 = fminf(cv0, __shfl_xor(cv0, 16, 64));
        cv0 = fminf(cv0, __shfl_xor(cv0, 32, 64));
        cv1 = fminf(cv1, __shfl_xor(cv1, 16, 64));
        cv1 = fminf(cv1, __shfl_xor(cv1, 32, 64));
        if (quad == 0) {   // plain LDS stores: exactly one writer per entry
            colbuf2[w >> 1][it * 64 + qc + lm]      = __float_as_uint(fmaxf(cv0, 0.f));
            colbuf2[w >> 1][it * 64 + qc + 16 + lm] = __float_as_uint(fmaxf(cv1, 0.f));
        }
        __syncthreads();   // buffer swap; drains only the B prefetch
    }

    // ---- colmin flush: merge rowhalves, one coalesced atomic pass ----
    #pragma unroll
    for (int e = 0; e < 4; ++e) {
        const int idx = tid * 4 + e;   // (it*64 + col) == linear col offset
        const unsigned int m = min(colbuf2[0][idx], colbuf2[1][idx]);
        atomicMin(&colmin[(size_t)b * M_ + panel * 1024 + idx], m);
    }

    // ---- row mins: butterfly across the 16 lane-cols ----
    #pragma unroll
    for (int s = 1; s < 16; s <<= 1)
        #pragma unroll
        for (int v = 0; v < 16; ++v)
            rv[v] = fminf(rv[v], __shfl_xor(rv[v], s, 64));
    if (lm == 0) {
        #pragma unroll
        for (int v = 0; v < 16; ++v)
            atomicMin(&rowmin[(size_t)b * N_ + row0 + wrow + 16 * (v >> 2) +
                              4 * quad + (v & 3)],
                      __float_as_uint(fmaxf(rv[v], 0.f)));
    }

    // ---- last block of this batch does the final reduction ----
    __syncthreads();                       // colbuf reads + atomics done
    if (tid == 0) {
        __threadfence();
        *s_last = (atomicAdd(&done_ctr[b], 1u) == 127u) ? 1u : 0u;
    }
    __syncthreads();
    if (*s_last) {
        __threadfence();
        float s = 0.f;
        for (int i = tid; i < N_; i += 256) {
            unsigned int ur = __hip_atomic_load(&rowmin[(size_t)b * N_ + i],
                                                __ATOMIC_RELAXED,
                                                __HIP_MEMORY_SCOPE_AGENT);
            unsigned int uc = __hip_atomic_load(&colmin[(size_t)b * M_ + i],
                                                __ATOMIC_RELAXED,
                                                __HIP_MEMORY_SCOPE_AGENT);
            s += sqrtf(fmaxf(__uint_as_float(ur), 0.f)) * (1.f / N_)
               + sqrtf(fmaxf(__uint_as_float(uc), 0.f)) * (1.f / M_);
        }
        #pragma unroll
        for (int off = 32; off > 0; off >>= 1) s += __shfl_down(s, off, 64);
        __syncthreads();                   // s_last read done before ws4 write
        if ((tid & 63) == 0) ws4[tid >> 6] = s;
        __syncthreads();
        if (tid == 0) out[b] = ws4[0] + ws4[1] + ws4[2] + ws4[3];
    }
}

extern "C" void kernel_launch(void* const* d_in, const int* in_sizes, int n_in,
                              void* d_out, int out_size, void* d_ws, size_t ws_size,
                              hipStream_t stream) {
    const float* s1 = (const float*)d_in[0];
    const float* s2 = (const float*)d_in[1];
    float* out = (float*)d_out;

    // ws: rowmin(BN u32) | colmin(BM u32) | norms(BN+BM f32) | bfA | bfB | done(8)
    unsigned int* rowmin = (unsigned int*)d_ws;
    unsigned int* colmin = rowmin + BN_;
    float* norms         = (float*)(colmin + BM_);
    unsigned short* bfA  = (unsigned short*)(norms + BN_ + BM_);
    unsigned short* bfB  = bfA + (size_t)BN_ * C_;
    unsigned int* done   = (unsigned int*)(bfB + (size_t)BM_ * C_);

    prep_kernel<<<(BN_ + BM_) / 16, 256, 0, stream>>>(
        s1, s2, rowmin, norms, bfA, bfB, out, done);

    dim3 grid(N_ / 128, M_ / 1024, B_);
    hausdorff_mfma<<<grid, 256, 0, stream>>>(
        bfA, bfB, norms, norms + BN_, rowmin, colmin, out, done);
}

// Round 11
// 130.065 us; speedup vs baseline: 1.2129x; 1.2129x over previous
//
#include <hip/hip_runtime.h>

// HausdorffLoss (average): B=8, N=M=4096, C=128, fp32 in/out.
// R11: barrier-free main kernel. Prep stores A/B bf16 in FRAGMENT-MAJOR
// layout (per 64-row tile: [half][j][c][lane] ushort8 chunks), so the main
// kernel streams B fragments straight into registers (ping-pong double
// buffer, prefetch 1 tile ahead) and holds A-frags in registers for the
// whole block. Zero LDS, zero __syncthreads, fire-and-forget atomics.
// Separate 8-block reduce kernel (R9/R10's fused reduce + threadfence
// regressed; reverted).
#define B_ 8
#define N_ 4096
#define M_ 4096
#define C_ 128
#define BN_ (B_ * N_)
#define BM_ (B_ * M_)

typedef __attribute__((ext_vector_type(8))) short bf16x8;    // MFMA A/B frag
typedef __attribute__((ext_vector_type(4))) float floatx4;   // MFMA C/D frag
typedef __attribute__((ext_vector_type(8))) unsigned short ushort8;

// fp32 -> bf16 round-to-nearest-even
__device__ __forceinline__ unsigned short f2bf(float x) {
    unsigned int u = __float_as_uint(x);
    u += 0x7FFFu + ((u >> 16) & 1u);
    return (unsigned short)(u >> 16);
}

// Fragment-major flat index (in ushort8 units) for (tile,half,j,c,lane):
//   ((((t*2 + h)*2 + j)*4 + c)*64 + lane)
// element (row m, k): t=m>>6, h=(m>>5)&1, j=(m>>4)&1, lm=m&15,
//                     c=k>>5, quad=(k>>3)&3, lane=quad*16+lm.

// ---------------------------------------------------------------------------
// Prep: fragment-major bf16 images for A and B + fp32 norms + minbuf init.
// One wave per (batch, img, tile, half, j) = 16 rows; lane (quad,lm) covers
// row (tile*64+half*32+j*16+lm), k-chunks c*32+quad*8 .. +7 (+ second f4).
// Grid = 1024 blocks x 256 threads (4096 wave-units).
// ---------------------------------------------------------------------------
__global__ __launch_bounds__(256) void prep_kernel(
    const float* __restrict__ S1, const float* __restrict__ S2,
    unsigned int* __restrict__ minbuf, float* __restrict__ norms,
    unsigned short* __restrict__ Afrag, unsigned short* __restrict__ Bfrag) {
    const int lane = threadIdx.x & 63;
    const int w    = threadIdx.x >> 6;
    const int lm   = lane & 15;
    const int quad = lane >> 4;

    const int unit  = blockIdx.x * 4 + w;      // 0..4095
    const int batch = unit >> 9;               // 0..7
    const int rem   = unit & 511;
    const int isB   = rem >> 8;                // 0:A(S1) 1:B(S2)
    const int q     = rem & 255;
    const int t     = q >> 2;                  // tile 0..63
    const int h     = (q >> 1) & 1;
    const int j     = q & 1;
    const int m     = t * 64 + h * 32 + j * 16 + lm;   // row in batch

    const float* src = (isB ? S2 : S1) + ((size_t)batch * 4096 + m) * C_;
    unsigned short* dst = (isB ? Bfrag : Afrag) + (size_t)batch * (4096 * C_)
                        + (size_t)(((t * 2 + h) * 2 + j) * 4) * 64 * 8;

    float s = 0.f;
    #pragma unroll
    for (int c = 0; c < 4; ++c) {
        float4 v0 = *(const float4*)(src + c * 32 + quad * 8);
        float4 v1 = *(const float4*)(src + c * 32 + quad * 8 + 4);
        s += v0.x*v0.x + v0.y*v0.y + v0.z*v0.z + v0.w*v0.w
           + v1.x*v1.x + v1.y*v1.y + v1.z*v1.z + v1.w*v1.w;
        ushort8 o;
        o[0] = f2bf(v0.x); o[1] = f2bf(v0.y); o[2] = f2bf(v0.z); o[3] = f2bf(v0.w);
        o[4] = f2bf(v1.x); o[5] = f2bf(v1.y); o[6] = f2bf(v1.z); o[7] = f2bf(v1.w);
        *(ushort8*)&dst[(size_t)(c * 64 + lane) * 8] = o;
    }
    // row norm: sum the 4 quad partials (lanes sharing lm)
    s += __shfl_xor(s, 16, 64);
    s += __shfl_xor(s, 32, 64);
    if (quad == 0) {
        const int gr = (isB ? BN_ : 0) + batch * 4096 + m;
        norms[gr]  = s;
        minbuf[gr] = 0x7F800000u;   // +inf
    }
}

// ---------------------------------------------------------------------------
// Main: grid (N/128, M/2048, B_). 4 waves; wave tile = 64 rows x 32 cols,
// sweeping 32 64-col B tiles. No LDS, no barriers.
// ---------------------------------------------------------------------------
__global__ __launch_bounds__(256, 2) void hausdorff_mfma(
    const unsigned short* __restrict__ Afrag, const unsigned short* __restrict__ Bfrag,
    const float* __restrict__ asq_g, const float* __restrict__ bsq_g,
    unsigned int* __restrict__ rowmin, unsigned int* __restrict__ colmin) {

    const int b     = blockIdx.z;
    const int row0  = blockIdx.x * 128;
    const int panel = blockIdx.y;              // cols panel*2048 ..
    const int tid   = threadIdx.x;
    const int lane  = tid & 63;
    const int w     = tid >> 6;
    const int lm    = lane & 15;
    const int quad  = lane >> 4;
    const int wrow  = (w >> 1) * 64;           // wave's row half
    const int wch   = w & 1;                   // wave's col half of each tile

    const unsigned short* Af = Afrag + (size_t)b * (4096 * C_);
    const unsigned short* Bf = Bfrag + (size_t)b * (4096 * C_);
    const int tA  = (row0 >> 6) + (w >> 1);
    const int tB0 = panel * 32;

    // A fragments, held for the whole block. af[i][c]: rows row0+wrow+16i+lm.
    bf16x8 af[4][4];
    #pragma unroll
    for (int i = 0; i < 4; ++i)
        #pragma unroll
        for (int c = 0; c < 4; ++c)
            af[i][c] = *(const bf16x8*)
                &Af[(size_t)(((((tA * 2 + (i >> 1)) * 2 + (i & 1)) * 4 + c) * 64 + lane)) * 8];

    // row norms for this lane's 16 rows: wrow + 16i + 4*quad + reg
    float sa[16];
    #pragma unroll
    for (int i = 0; i < 4; ++i) {
        float4 t = *(const float4*)&asq_g[(size_t)b * N_ + row0 + wrow + 16 * i + 4 * quad];
        sa[4*i+0] = t.x; sa[4*i+1] = t.y; sa[4*i+2] = t.z; sa[4*i+3] = t.w;
    }

    float rv[16];
    #pragma unroll
    for (int v = 0; v < 16; ++v) rv[v] = 1e30f;

    auto loadB = [&](bf16x8 (&d)[2][4], int it) {
        const unsigned short* base =
            &Bf[(size_t)(((tB0 + it) * 2 + wch) * 2) * 4 * 64 * 8];
        #pragma unroll
        for (int j = 0; j < 2; ++j)
            #pragma unroll
            for (int c = 0; c < 4; ++c)
                d[j][c] = *(const bf16x8*)&base[(size_t)((j * 4 + c) * 64 + lane) * 8];
    };

    auto compute = [&](bf16x8 (&bfr)[2][4], int it) {
        const int colbase = panel * 2048 + it * 64 + wch * 32;
        const float sb0 = bsq_g[(size_t)b * M_ + colbase + lm];
        const float sb1 = bsq_g[(size_t)b * M_ + colbase + 16 + lm];

        floatx4 acc[4][2] = {};
        #pragma unroll
        for (int c = 0; c < 4; ++c)
            #pragma unroll
            for (int i = 0; i < 4; ++i)
                #pragma unroll
                for (int j = 0; j < 2; ++j)
                    acc[i][j] = __builtin_amdgcn_mfma_f32_16x16x32_bf16(
                        af[i][c], bfr[j][c], acc[i][j], 0, 0, 0);

        float cv0 = 1e30f, cv1 = 1e30f;
        #pragma unroll
        for (int i = 0; i < 4; ++i)
            #pragma unroll
            for (int reg = 0; reg < 4; ++reg) {
                const int v = 4 * i + reg;
                float d0 = fmaf(-2.0f, acc[i][0][reg], sa[v] + sb0);
                float d1 = fmaf(-2.0f, acc[i][1][reg], sa[v] + sb1);
                rv[v] = fminf(rv[v], fminf(d0, d1));
                cv0 = fminf(cv0, d0);
                cv1 = fminf(cv1, d1);
            }
        cv0 = fminf(cv0, __shfl_xor(cv0, 16, 64));
        cv0 = fminf(cv0, __shfl_xor(cv0, 32, 64));
        cv1 = fminf(cv1, __shfl_xor(cv1, 16, 64));
        cv1 = fminf(cv1, __shfl_xor(cv1, 32, 64));
        if (quad == 0) {   // fire-and-forget: nothing waits on these
            atomicMin(&colmin[(size_t)b * M_ + colbase + lm],
                      __float_as_uint(fmaxf(cv0, 0.f)));
            atomicMin(&colmin[(size_t)b * M_ + colbase + 16 + lm],
                      __float_as_uint(fmaxf(cv1, 0.f)));
        }
    };

    // ping-pong register double buffer over the 32 B tiles
    bf16x8 bfP[2][4], bfQ[2][4];
    loadB(bfP, 0);
    for (int it2 = 0; it2 < 32; it2 += 2) {
        loadB(bfQ, it2 + 1);
        compute(bfP, it2);
        if (it2 < 30) loadB(bfP, it2 + 2);
        compute(bfQ, it2 + 1);
    }

    // row mins: butterfly across the 16 lane-cols
    #pragma unroll
    for (int s = 1; s < 16; s <<= 1)
        #pragma unroll
        for (int v = 0; v < 16; ++v)
            rv[v] = fminf(rv[v], __shfl_xor(rv[v], s, 64));
    if (lm == 0) {
        #pragma unroll
        for (int v = 0; v < 16; ++v)
            atomicMin(&rowmin[(size_t)b * N_ + row0 + wrow + 16 * (v >> 2) +
                              4 * quad + (v & 3)],
                      __float_as_uint(fmaxf(rv[v], 0.f)));
    }
}

// ---------------------------------------------------------------------------
// Reduce: one block per batch, direct write (no atomics, no init needed).
// ---------------------------------------------------------------------------
__global__ __launch_bounds__(256) void hausdorff_reduce(
    const unsigned int* __restrict__ rowmin,
    const unsigned int* __restrict__ colmin, float* __restrict__ out) {
    __shared__ float ws4[4];
    const int b = blockIdx.x;
    float s = 0.f;
    for (int i = threadIdx.x; i < N_; i += 256)
        s += sqrtf(fmaxf(__uint_as_float(rowmin[(size_t)b * N_ + i]), 0.f)) * (1.f / N_)
           + sqrtf(fmaxf(__uint_as_float(colmin[(size_t)b * M_ + i]), 0.f)) * (1.f / M_);
    #pragma unroll
    for (int off = 32; off > 0; off >>= 1) s += __shfl_down(s, off, 64);
    if ((threadIdx.x & 63) == 0) ws4[threadIdx.x >> 6] = s;
    __syncthreads();
    if (threadIdx.x == 0)
        out[b] = ws4[0] + ws4[1] + ws4[2] + ws4[3];
}

extern "C" void kernel_launch(void* const* d_in, const int* in_sizes, int n_in,
                              void* d_out, int out_size, void* d_ws, size_t ws_size,
                              hipStream_t stream) {
    const float* s1 = (const float*)d_in[0];
    const float* s2 = (const float*)d_in[1];
    float* out = (float*)d_out;

    // ws: rowmin(BN u32) | colmin(BM u32) | norms(BN+BM f32) | Afrag | Bfrag
    unsigned int* rowmin  = (unsigned int*)d_ws;
    unsigned int* colmin  = rowmin + BN_;
    float* norms          = (float*)(colmin + BM_);
    unsigned short* Afrag = (unsigned short*)(norms + BN_ + BM_);
    unsigned short* Bfrag = Afrag + (size_t)BN_ * C_;

    prep_kernel<<<1024, 256, 0, stream>>>(s1, s2, rowmin, norms, Afrag, Bfrag);

    dim3 grid(N_ / 128, M_ / 2048, B_);
    hausdorff_mfma<<<grid, 256, 0, stream>>>(
        Afrag, Bfrag, norms, norms + BN_, rowmin, colmin);

    hausdorff_reduce<<<B_, 256, 0, stream>>>(rowmin, colmin, out);
}

// Round 12
// 126.097 us; speedup vs baseline: 1.2511x; 1.0315x over previous
//
#include <hip/hip_runtime.h>

// HausdorffLoss (average): B=8, N=M=4096, C=128, fp32 in/out.
// R12 = R11 (barrier-free, fragment-major ws images, register ping-pong B)
// + grid 1024 blocks (1024-col panels -> 4 blocks/CU resident; B traffic
// is panel-width invariant) + max-form epilogue with sb register-prefetch
// (acc init = -(sa+sb)/2, post-MFMA d2 = -2*acc: kills 32 fma/iter; R9's
// regression was sb loads inside the MFMA dependency cone — prefetching
// them a tile ahead fixes that).
#define B_ 8
#define N_ 4096
#define M_ 4096
#define C_ 128
#define BN_ (B_ * N_)
#define BM_ (B_ * M_)

typedef __attribute__((ext_vector_type(8))) short bf16x8;    // MFMA A/B frag
typedef __attribute__((ext_vector_type(4))) float floatx4;   // MFMA C/D frag
typedef __attribute__((ext_vector_type(8))) unsigned short ushort8;

// fp32 -> bf16 round-to-nearest-even
__device__ __forceinline__ unsigned short f2bf(float x) {
    unsigned int u = __float_as_uint(x);
    u += 0x7FFFu + ((u >> 16) & 1u);
    return (unsigned short)(u >> 16);
}

// Fragment-major flat index (in ushort8 units) for (tile,half,j,c,lane):
//   ((((t*2 + h)*2 + j)*4 + c)*64 + lane)
// element (row m, k): t=m>>6, h=(m>>5)&1, j=(m>>4)&1, lm=m&15,
//                     c=k>>5, quad=(k>>3)&3, lane=quad*16+lm.

// ---------------------------------------------------------------------------
// Prep: fragment-major bf16 images for A and B + fp32 norms + minbuf init.
// One wave per (batch, img, tile, half, j) = 16 rows.
// Grid = 1024 blocks x 256 threads (4096 wave-units).
// ---------------------------------------------------------------------------
__global__ __launch_bounds__(256) void prep_kernel(
    const float* __restrict__ S1, const float* __restrict__ S2,
    unsigned int* __restrict__ minbuf, float* __restrict__ norms,
    unsigned short* __restrict__ Afrag, unsigned short* __restrict__ Bfrag) {
    const int lane = threadIdx.x & 63;
    const int w    = threadIdx.x >> 6;
    const int lm   = lane & 15;
    const int quad = lane >> 4;

    const int unit  = blockIdx.x * 4 + w;      // 0..4095
    const int batch = unit >> 9;               // 0..7
    const int rem   = unit & 511;
    const int isB   = rem >> 8;                // 0:A(S1) 1:B(S2)
    const int q     = rem & 255;
    const int t     = q >> 2;                  // tile 0..63
    const int h     = (q >> 1) & 1;
    const int j     = q & 1;
    const int m     = t * 64 + h * 32 + j * 16 + lm;   // row in batch

    const float* src = (isB ? S2 : S1) + ((size_t)batch * 4096 + m) * C_;
    unsigned short* dst = (isB ? Bfrag : Afrag) + (size_t)batch * (4096 * C_)
                        + (size_t)(((t * 2 + h) * 2 + j) * 4) * 64 * 8;

    float s = 0.f;
    #pragma unroll
    for (int c = 0; c < 4; ++c) {
        float4 v0 = *(const float4*)(src + c * 32 + quad * 8);
        float4 v1 = *(const float4*)(src + c * 32 + quad * 8 + 4);
        s += v0.x*v0.x + v0.y*v0.y + v0.z*v0.z + v0.w*v0.w
           + v1.x*v1.x + v1.y*v1.y + v1.z*v1.z + v1.w*v1.w;
        ushort8 o;
        o[0] = f2bf(v0.x); o[1] = f2bf(v0.y); o[2] = f2bf(v0.z); o[3] = f2bf(v0.w);
        o[4] = f2bf(v1.x); o[5] = f2bf(v1.y); o[6] = f2bf(v1.z); o[7] = f2bf(v1.w);
        *(ushort8*)&dst[(size_t)(c * 64 + lane) * 8] = o;
    }
    // row norm: sum the 4 quad partials (lanes sharing lm)
    s += __shfl_xor(s, 16, 64);
    s += __shfl_xor(s, 32, 64);
    if (quad == 0) {
        const int gr = (isB ? BN_ : 0) + batch * 4096 + m;
        norms[gr]  = s;
        minbuf[gr] = 0x7F800000u;   // +inf
    }
}

// ---------------------------------------------------------------------------
// Main: grid (N/128, M/1024, B_). 4 waves; wave tile = 64 rows x 32 cols,
// sweeping 16 64-col B tiles. No LDS, no barriers.
// ---------------------------------------------------------------------------
__global__ __launch_bounds__(256, 2) void hausdorff_mfma(
    const unsigned short* __restrict__ Afrag, const unsigned short* __restrict__ Bfrag,
    const float* __restrict__ asq_g, const float* __restrict__ bsq_g,
    unsigned int* __restrict__ rowmin, unsigned int* __restrict__ colmin) {

    const int b     = blockIdx.z;
    const int row0  = blockIdx.x * 128;
    const int panel = blockIdx.y;              // cols panel*1024 ..
    const int tid   = threadIdx.x;
    const int lane  = tid & 63;
    const int w     = tid >> 6;
    const int lm    = lane & 15;
    const int quad  = lane >> 4;
    const int wrow  = (w >> 1) * 64;           // wave's row half
    const int wch   = w & 1;                   // wave's col half of each tile

    const unsigned short* Af = Afrag + (size_t)b * (4096 * C_);
    const unsigned short* Bf = Bfrag + (size_t)b * (4096 * C_);
    const int tA  = (row0 >> 6) + (w >> 1);
    const int tB0 = panel * 16;

    // A fragments, held for the whole block. af[i][c]: rows row0+wrow+16i+lm.
    bf16x8 af[4][4];
    #pragma unroll
    for (int i = 0; i < 4; ++i)
        #pragma unroll
        for (int c = 0; c < 4; ++c)
            af[i][c] = *(const bf16x8*)
                &Af[(size_t)(((((tA * 2 + (i >> 1)) * 2 + (i & 1)) * 4 + c) * 64 + lane)) * 8];

    // -0.5 * row norms for this lane's 16 rows: wrow + 16i + 4*quad + reg
    float sah[16];
    #pragma unroll
    for (int i = 0; i < 4; ++i) {
        float4 t = *(const float4*)&asq_g[(size_t)b * N_ + row0 + wrow + 16 * i + 4 * quad];
        sah[4*i+0] = -0.5f * t.x; sah[4*i+1] = -0.5f * t.y;
        sah[4*i+2] = -0.5f * t.z; sah[4*i+3] = -0.5f * t.w;
    }

    float rv[16];   // max of acc' = I - (sa+sb)/2  (bigger == smaller d2)
    #pragma unroll
    for (int v = 0; v < 16; ++v) rv[v] = -1e30f;

    auto loadB = [&](bf16x8 (&d)[2][4], int it) {
        const unsigned short* base =
            &Bf[(size_t)(((tB0 + it) * 2 + wch) * 2) * 4 * 64 * 8];
        #pragma unroll
        for (int j = 0; j < 2; ++j)
            #pragma unroll
            for (int c = 0; c < 4; ++c)
                d[j][c] = *(const bf16x8*)&base[(size_t)((j * 4 + c) * 64 + lane) * 8];
    };

    auto loadSb = [&](float& n0, float& n1, int it) {
        const int colbase = panel * 1024 + it * 64 + wch * 32;
        n0 = -0.5f * bsq_g[(size_t)b * M_ + colbase + lm];
        n1 = -0.5f * bsq_g[(size_t)b * M_ + colbase + 16 + lm];
    };

    auto compute = [&](bf16x8 (&bfr)[2][4], int it, float nb0, float nb1) {
        const int colbase = panel * 1024 + it * 64 + wch * 32;

        // acc init = -(sa+sb)/2 (resident regs); after MFMA acc = -d2/2
        floatx4 acc[4][2];
        #pragma unroll
        for (int i = 0; i < 4; ++i)
            #pragma unroll
            for (int reg = 0; reg < 4; ++reg) {
                acc[i][0][reg] = sah[4*i+reg] + nb0;
                acc[i][1][reg] = sah[4*i+reg] + nb1;
            }

        #pragma unroll
        for (int c = 0; c < 4; ++c)
            #pragma unroll
            for (int i = 0; i < 4; ++i)
                #pragma unroll
                for (int j = 0; j < 2; ++j)
                    acc[i][j] = __builtin_amdgcn_mfma_f32_16x16x32_bf16(
                        af[i][c], bfr[j][c], acc[i][j], 0, 0, 0);

        float cv0 = -1e30f, cv1 = -1e30f;
        #pragma unroll
        for (int i = 0; i < 4; ++i)
            #pragma unroll
            for (int reg = 0; reg < 4; ++reg) {
                const int v = 4 * i + reg;
                rv[v] = fmaxf(rv[v], fmaxf(acc[i][0][reg], acc[i][1][reg]));  // v_max3
                cv0 = fmaxf(cv0, acc[i][0][reg]);
                cv1 = fmaxf(cv1, acc[i][1][reg]);
            }
        cv0 = fmaxf(cv0, __shfl_xor(cv0, 16, 64));
        cv0 = fmaxf(cv0, __shfl_xor(cv0, 32, 64));
        cv1 = fmaxf(cv1, __shfl_xor(cv1, 16, 64));
        cv1 = fmaxf(cv1, __shfl_xor(cv1, 32, 64));
        if (quad == 0) {   // fire-and-forget: nothing waits on these
            atomicMin(&colmin[(size_t)b * M_ + colbase + lm],
                      __float_as_uint(fmaxf(-2.0f * cv0, 0.f)));
            atomicMin(&colmin[(size_t)b * M_ + colbase + 16 + lm],
                      __float_as_uint(fmaxf(-2.0f * cv1, 0.f)));
        }
    };

    // ping-pong register double buffer over the 16 B tiles (+ sb prefetch)
    bf16x8 bfP[2][4], bfQ[2][4];
    float nbP0, nbP1, nbQ0, nbQ1;
    loadB(bfP, 0);
    loadSb(nbP0, nbP1, 0);
    for (int it2 = 0; it2 < 16; it2 += 2) {
        loadB(bfQ, it2 + 1);
        loadSb(nbQ0, nbQ1, it2 + 1);
        compute(bfP, it2, nbP0, nbP1);
        if (it2 < 14) {
            loadB(bfP, it2 + 2);
            loadSb(nbP0, nbP1, it2 + 2);
        }
        compute(bfQ, it2 + 1, nbQ0, nbQ1);
    }

    // row maxes -> butterfly across the 16 lane-cols, then d2 = -2*rv
    #pragma unroll
    for (int s = 1; s < 16; s <<= 1)
        #pragma unroll
        for (int v = 0; v < 16; ++v)
            rv[v] = fmaxf(rv[v], __shfl_xor(rv[v], s, 64));
    if (lm == 0) {
        #pragma unroll
        for (int v = 0; v < 16; ++v)
            atomicMin(&rowmin[(size_t)b * N_ + row0 + wrow + 16 * (v >> 2) +
                              4 * quad + (v & 3)],
                      __float_as_uint(fmaxf(-2.0f * rv[v], 0.f)));
    }
}

// ---------------------------------------------------------------------------
// Reduce: one block per batch, direct write.
// ---------------------------------------------------------------------------
__global__ __launch_bounds__(256) void hausdorff_reduce(
    const unsigned int* __restrict__ rowmin,
    const unsigned int* __restrict__ colmin, float* __restrict__ out) {
    __shared__ float ws4[4];
    const int b = blockIdx.x;
    float s = 0.f;
    for (int i = threadIdx.x; i < N_; i += 256)
        s += sqrtf(fmaxf(__uint_as_float(rowmin[(size_t)b * N_ + i]), 0.f)) * (1.f / N_)
           + sqrtf(fmaxf(__uint_as_float(colmin[(size_t)b * M_ + i]), 0.f)) * (1.f / M_);
    #pragma unroll
    for (int off = 32; off > 0; off >>= 1) s += __shfl_down(s, off, 64);
    if ((threadIdx.x & 63) == 0) ws4[threadIdx.x >> 6] = s;
    __syncthreads();
    if (threadIdx.x == 0)
        out[b] = ws4[0] + ws4[1] + ws4[2] + ws4[3];
}

extern "C" void kernel_launch(void* const* d_in, const int* in_sizes, int n_in,
                              void* d_out, int out_size, void* d_ws, size_t ws_size,
                              hipStream_t stream) {
    const float* s1 = (const float*)d_in[0];
    const float* s2 = (const float*)d_in[1];
    float* out = (float*)d_out;

    // ws: rowmin(BN u32) | colmin(BM u32) | norms(BN+BM f32) | Afrag | Bfrag
    unsigned int* rowmin  = (unsigned int*)d_ws;
    unsigned int* colmin  = rowmin + BN_;
    float* norms          = (float*)(colmin + BM_);
    unsigned short* Afrag = (unsigned short*)(norms + BN_ + BM_);
    unsigned short* Bfrag = Afrag + (size_t)BN_ * C_;

    prep_kernel<<<1024, 256, 0, stream>>>(s1, s2, rowmin, norms, Afrag, Bfrag);

    dim3 grid(N_ / 128, M_ / 1024, B_);
    hausdorff_mfma<<<grid, 256, 0, stream>>>(
        Afrag, Bfrag, norms, norms + BN_, rowmin, colmin);

    hausdorff_reduce<<<B_, 256, 0, stream>>>(rowmin, colmin, out);
}